// Round 1
// baseline (761.398 us; speedup 1.0000x reference)
//
#include <hip/hip_runtime.h>
#include <hip/hip_bf16.h>

#define NR 4096
#define DD 512
#define BM 128
#define BN 128
#define BK 64
#define LDK 72   // BK + 8 pad: row stride 144 B (16B-aligned, breaks 32-bank pow2 stride)

typedef __bf16 bf16x8 __attribute__((ext_vector_type(8)));
typedef float f32x4 __attribute__((ext_vector_type(4)));
typedef unsigned short u16;

__device__ __forceinline__ u16 f2bf(float x) {
    __hip_bfloat16 h = __float2bfloat16(x);
    return *reinterpret_cast<u16*>(&h);
}

// ---------------------------------------------------------------------------
// Kernel 1: row-normalize z1,z2 -> bf16, and d12[i] = zn1[i]·zn2[i] (fp32)
// ---------------------------------------------------------------------------
__global__ void norm_kernel(const float* z1, const float* z2,
                            u16* zn1, u16* zn2, float* d12) {
    const int row = blockIdx.x;
    const int t = threadIdx.x;           // 256 threads
    const float* r1 = z1 + (size_t)row * DD;
    const float* r2 = z2 + (size_t)row * DD;
    float a0 = r1[t], a1 = r1[t + 256];
    float b0 = r2[t], b1 = r2[t + 256];
    float ss1 = a0 * a0 + a1 * a1;
    float ss2 = b0 * b0 + b1 * b1;
    #pragma unroll
    for (int m = 1; m < 64; m <<= 1) {
        ss1 += __shfl_xor(ss1, m);
        ss2 += __shfl_xor(ss2, m);
    }
    __shared__ float s1s[4], s2s[4], ds[4];
    const int wid = t >> 6, lane = t & 63;
    if (lane == 0) { s1s[wid] = ss1; s2s[wid] = ss2; }
    __syncthreads();
    const float n1 = s1s[0] + s1s[1] + s1s[2] + s1s[3];
    const float n2 = s2s[0] + s2s[1] + s2s[2] + s2s[3];
    const float inv1 = 1.0f / fmaxf(sqrtf(n1), 1e-12f);
    const float inv2 = 1.0f / fmaxf(sqrtf(n2), 1e-12f);
    const float u0 = a0 * inv1, u1 = a1 * inv1;
    const float v0 = b0 * inv2, v1 = b1 * inv2;
    zn1[(size_t)row * DD + t]       = f2bf(u0);
    zn1[(size_t)row * DD + t + 256] = f2bf(u1);
    zn2[(size_t)row * DD + t]       = f2bf(v0);
    zn2[(size_t)row * DD + t + 256] = f2bf(v1);
    float dp = u0 * v0 + u1 * v1;
    #pragma unroll
    for (int m = 1; m < 64; m <<= 1) dp += __shfl_xor(dp, m);
    if (lane == 0) ds[wid] = dp;
    __syncthreads();
    if (t == 0) d12[row] = ds[0] + ds[1] + ds[2] + ds[3];
}

// ---------------------------------------------------------------------------
// Kernel 2: fused dual-GEMM + exp + (masked) row reductions.
// blockIdx.z==0: A=zn1[I], B1=zn1[J] (S11, logical pass 0), B2=zn2[J] (S12, pass 1),
//                adj set {c,m,f}, tau1-mask uses adj_c, tau2-mask uses adj_m.
// blockIdx.z==1: A=zn2[I], B1=zn2[J] (S22, pass 2), B2=zn1[J] (S21, pass 3),
//                adj set {c_aug,m_aug,f_aug}, tau1/tau2 masks both use f_aug.
// Accumulators (global, fp32, atomicAdd):
//   rs[pass][tau][i]  : full row sums of exp(S/tau)        (4*3*NR)
//   ms[pass][k][i]    : masked row sums, k=0..4            (4*5*NR)
//   asum[a][i]        : adjacency row counts, a=0..5       (6*NR)
// ---------------------------------------------------------------------------
__global__ __launch_bounds__(256, 2)
void score_kernel(const u16* zn1, const u16* zn2,
                  const float* ac, const float* am, const float* af,
                  const float* aca, const float* ama, const float* afa,
                  float* rs, float* ms, float* asum) {
    const int z = blockIdx.z;
    const int Ib = blockIdx.y * BM;
    const int Jb = blockIdx.x * BN;
    const u16* Ag  = z ? zn2 : zn1;
    const u16* B1g = z ? zn2 : zn1;
    const u16* B2g = z ? zn1 : zn2;
    const float* A1 = z ? aca : ac;
    const float* A2 = z ? ama : am;
    const float* A3 = z ? afa : af;

    __shared__ u16 As[BM][LDK];
    __shared__ u16 Bs1[BN][LDK];
    __shared__ u16 Bs2[BN][LDK];

    const int tid = threadIdx.x;
    const int lane = tid & 63;
    const int wid = tid >> 6;
    const int wm = wid >> 1, wn = wid & 1;   // 2x2 waves, 64x64 each
    const int quad = lane >> 4, lcol = lane & 15;

    f32x4 acc1[4][4], acc2[4][4];
    #pragma unroll
    for (int a = 0; a < 4; a++)
        #pragma unroll
        for (int b = 0; b < 4; b++) {
            acc1[a][b] = (f32x4){0.f, 0.f, 0.f, 0.f};
            acc2[a][b] = (f32x4){0.f, 0.f, 0.f, 0.f};
        }

    const int srow = tid >> 1;      // 0..127
    const int shalf = tid & 1;      // 0,1 : 32 bf16 each
    const size_t gA0 = (size_t)(Ib + srow) * DD + shalf * 32;
    const size_t gB0 = (size_t)(Jb + srow) * DD + shalf * 32;

    for (int k0 = 0; k0 < DD; k0 += BK) {
        const u16* pa  = Ag  + gA0 + k0;
        const u16* pb1 = B1g + gB0 + k0;
        const u16* pb2 = B2g + gB0 + k0;
        uint4 va[4], vb1[4], vb2[4];
        #pragma unroll
        for (int q = 0; q < 4; q++) {
            va[q]  = ((const uint4*)pa)[q];
            vb1[q] = ((const uint4*)pb1)[q];
            vb2[q] = ((const uint4*)pb2)[q];
        }
        __syncthreads();   // previous iteration's frag reads done before overwrite
        #pragma unroll
        for (int q = 0; q < 4; q++) {
            ((uint4*)&As[srow][shalf * 32])[q]  = va[q];
            ((uint4*)&Bs1[srow][shalf * 32])[q] = vb1[q];
            ((uint4*)&Bs2[srow][shalf * 32])[q] = vb2[q];
        }
        __syncthreads();
        #pragma unroll
        for (int kk = 0; kk < BK; kk += 32) {
            bf16x8 a[4], b1[4], b2[4];
            #pragma unroll
            for (int i = 0; i < 4; i++) {
                a[i]  = *(const bf16x8*)&As[wm * 64 + i * 16 + lcol][kk + quad * 8];
                b1[i] = *(const bf16x8*)&Bs1[wn * 64 + i * 16 + lcol][kk + quad * 8];
                b2[i] = *(const bf16x8*)&Bs2[wn * 64 + i * 16 + lcol][kk + quad * 8];
            }
            #pragma unroll
            for (int mi = 0; mi < 4; mi++)
                #pragma unroll
                for (int ni = 0; ni < 4; ni++) {
                    acc1[mi][ni] = __builtin_amdgcn_mfma_f32_16x16x32_bf16(a[mi], b1[ni], acc1[mi][ni], 0, 0, 0);
                    acc2[mi][ni] = __builtin_amdgcn_mfma_f32_16x16x32_bf16(a[mi], b2[ni], acc2[mi][ni], 0, 0, 0);
                }
        }
    }

    // exp(x/tau) = exp2(x * log2(e)/tau)
    const float C0 = 1.8033688011112042f;  // log2(e)/0.80
    const float C1 = 2.2542110013890054f;  // log2(e)/0.64
    const float C2 = 2.0037431123457825f;  // log2(e)/0.72

    #pragma unroll
    for (int mi = 0; mi < 4; mi++) {
        #pragma unroll
        for (int reg = 0; reg < 4; reg++) {
            const int i = Ib + wm * 64 + mi * 16 + quad * 4 + reg;   // C/D: row = quad*4+reg
            float p[19];
            #pragma unroll
            for (int q = 0; q < 19; q++) p[q] = 0.f;
            #pragma unroll
            for (int ni = 0; ni < 4; ni++) {
                const int j = Jb + wn * 64 + ni * 16 + lcol;          // C/D: col = lane&15
                const size_t off = (size_t)i * NR + j;
                const float a1 = A1[off], a2 = A2[off], a3 = A3[off];
                const float s1 = acc1[mi][ni][reg];
                const float s2 = acc2[mi][ni][reg];
                const float e10 = __builtin_amdgcn_exp2f(s1 * C0);
                const float e11 = __builtin_amdgcn_exp2f(s1 * C1);
                const float e12 = __builtin_amdgcn_exp2f(s1 * C2);
                const float e20 = __builtin_amdgcn_exp2f(s2 * C0);
                const float e21 = __builtin_amdgcn_exp2f(s2 * C1);
                const float e22 = __builtin_amdgcn_exp2f(s2 * C2);
                const float ax = z ? a3 : a1;
                const float ay = z ? a3 : a2;
                p[0] += e10; p[1] += e11; p[2] += e12;
                p[3] += a1 * e10; p[4] += a2 * e10; p[5] += a3 * e10;
                p[6] += ax * e11; p[7] += ay * e12;
                p[8] += e20; p[9] += e21; p[10] += e22;
                p[11] += a1 * e20; p[12] += a2 * e20; p[13] += a3 * e20;
                p[14] += ax * e21; p[15] += ay * e22;
                p[16] += a1; p[17] += a2; p[18] += a3;
            }
            #pragma unroll
            for (int q = 0; q < 19; q++) {
                p[q] += __shfl_xor(p[q], 1);
                p[q] += __shfl_xor(p[q], 2);
                p[q] += __shfl_xor(p[q], 4);
                p[q] += __shfl_xor(p[q], 8);
            }
            if (lcol == 0) {
                const int p1 = 2 * z, p2 = 2 * z + 1;
                atomicAdd(&rs[(p1 * 3 + 0) * NR + i], p[0]);
                atomicAdd(&rs[(p1 * 3 + 1) * NR + i], p[1]);
                atomicAdd(&rs[(p1 * 3 + 2) * NR + i], p[2]);
                atomicAdd(&ms[(p1 * 5 + 0) * NR + i], p[3]);
                atomicAdd(&ms[(p1 * 5 + 1) * NR + i], p[4]);
                atomicAdd(&ms[(p1 * 5 + 2) * NR + i], p[5]);
                atomicAdd(&ms[(p1 * 5 + 3) * NR + i], p[6]);
                atomicAdd(&ms[(p1 * 5 + 4) * NR + i], p[7]);
                atomicAdd(&rs[(p2 * 3 + 0) * NR + i], p[8]);
                atomicAdd(&rs[(p2 * 3 + 1) * NR + i], p[9]);
                atomicAdd(&rs[(p2 * 3 + 2) * NR + i], p[10]);
                atomicAdd(&ms[(p2 * 5 + 0) * NR + i], p[11]);
                atomicAdd(&ms[(p2 * 5 + 1) * NR + i], p[12]);
                atomicAdd(&ms[(p2 * 5 + 2) * NR + i], p[13]);
                atomicAdd(&ms[(p2 * 5 + 3) * NR + i], p[14]);
                atomicAdd(&ms[(p2 * 5 + 4) * NR + i], p[15]);
                atomicAdd(&asum[(3 * z + 0) * NR + i], p[16]);
                atomicAdd(&asum[(3 * z + 1) * NR + i], p[17]);
                atomicAdd(&asum[(3 * z + 2) * NR + i], p[18]);
            }
        }
    }
}

// ---------------------------------------------------------------------------
// Kernel 3: assemble the 10 losses and the final scalar.
// ---------------------------------------------------------------------------
__global__ void finalize_kernel(const float* rs, const float* ms, const float* asum,
                                const float* d12, float* out) {
    const int t = threadIdx.x;   // 256
    // A-calls: (tau, ms-slot k, adj a): (0,0,c)(0,1,m)(0,2,f)(1,3,c)(2,4,m)
    // B-calls: same tau/k with aug adj: c_aug,m_aug,f_aug,f_aug,f_aug
    const int tA[5] = {0, 0, 0, 1, 2};
    const int kA[5] = {0, 1, 2, 3, 4};
    const int aA[5] = {0, 1, 2, 0, 1};
    const int aB[5] = {3, 4, 5, 5, 5};
    const float it[3] = {1.25f, 1.5625f, 1.3888888888888888f};
    const float e1t[3] = {expf(1.25f), expf(1.5625f), expf(1.3888888888888888f)};

    float LA[5] = {0, 0, 0, 0, 0}, LB[5] = {0, 0, 0, 0, 0};
    float sc = 0.f, sm = 0.f, sf = 0.f;

    for (int i = t; i < NR; i += 256) {
        const float d = d12[i];
        float ed[3];
        ed[0] = __expf(d * it[0]); ed[1] = __expf(d * it[1]); ed[2] = __expf(d * it[2]);
        float R[4][3], M[4][5], A6[6];
        #pragma unroll
        for (int p = 0; p < 4; p++) {
            #pragma unroll
            for (int tt = 0; tt < 3; tt++) R[p][tt] = rs[(p * 3 + tt) * NR + i];
            #pragma unroll
            for (int k = 0; k < 5; k++) M[p][k] = ms[(p * 5 + k) * NR + i];
        }
        #pragma unroll
        for (int a = 0; a < 6; a++) A6[a] = asum[a * NR + i];

        #pragma unroll
        for (int c = 0; c < 5; c++) {
            const int tt = tA[c], k = kA[c];
            // A-call: intra=pass0(S11), inter=pass1(S12)
            float pos = ed[tt] + M[0][k] + M[1][k];
            float den = R[0][tt] + R[1][tt] - e1t[tt];
            float cnt = 2.f * A6[aA[c]] + 1.f;
            LA[c] += __logf(pos / den) / cnt;
            // B-call: intra=pass2(S22), inter=pass3(S21)
            pos = ed[tt] + M[2][k] + M[3][k];
            den = R[2][tt] + R[3][tt] - e1t[tt];
            cnt = 2.f * A6[aB[c]] + 1.f;
            LB[c] += __logf(pos / den) / cnt;
        }
        sc += A6[0]; sm += A6[1]; sf += A6[2];
    }

    __shared__ float red[256];
    float vals[13] = {LA[0], LA[1], LA[2], LA[3], LA[4],
                      LB[0], LB[1], LB[2], LB[3], LB[4], sc, sm, sf};
    __shared__ float tot[13];
    for (int q = 0; q < 13; q++) {
        red[t] = vals[q];
        __syncthreads();
        for (int s = 128; s > 0; s >>= 1) {
            if (t < s) red[t] += red[t + s];
            __syncthreads();
        }
        if (t == 0) tot[q] = red[0];
        __syncthreads();
    }
    if (t == 0) {
        float Ac[5], Bc[5];
        #pragma unroll
        for (int c = 0; c < 5; c++) {
            Ac[c] = -tot[c] / (float)NR;
            Bc[c] = -tot[5 + c] / (float)NR;
        }
        const float ALPHA = 0.55f, BETA = 0.4f;
        const float Lc  = ALPHA * Ac[0] + BETA * Bc[0];
        const float Lm  = ALPHA * Ac[1] + BETA * Bc[1];
        const float Lf  = ALPHA * Ac[2] + BETA * Bc[2];
        const float Lcf = ALPHA * Ac[3] + BETA * Bc[3];
        const float Lmf = ALPHA * Ac[4] + BETA * Bc[4];
        const float scs = tot[10], sms = tot[11], sfs = tot[12];
        const float tot_info = scs + sms + sfs + 1e-8f;
        out[0] = (scs * Lc + sms * Lm + sfs * Lf) / tot_info + 0.2f * (Lcf + Lmf);
    }
}

extern "C" void kernel_launch(void* const* d_in, const int* in_sizes, int n_in,
                              void* d_out, int out_size, void* d_ws, size_t ws_size,
                              hipStream_t stream) {
    const float* z1  = (const float*)d_in[0];
    const float* z2  = (const float*)d_in[1];
    const float* ac  = (const float*)d_in[2];
    const float* am  = (const float*)d_in[3];
    const float* af  = (const float*)d_in[4];
    const float* aca = (const float*)d_in[5];
    const float* ama = (const float*)d_in[6];
    const float* afa = (const float*)d_in[7];

    float* ws   = (float*)d_ws;
    float* rs   = ws;                       // 12*NR
    float* ms   = rs + 12 * NR;             // 20*NR
    float* asum = ms + 20 * NR;             // 6*NR
    float* d12  = asum + 6 * NR;            // NR
    u16* zn1 = (u16*)(d12 + NR);            // NR*DD bf16
    u16* zn2 = zn1 + (size_t)NR * DD;

    hipMemsetAsync(ws, 0, (12 + 20 + 6) * NR * sizeof(float), stream);
    norm_kernel<<<NR, 256, 0, stream>>>(z1, z2, zn1, zn2, d12);
    dim3 grid(NR / BN, NR / BM, 2);
    score_kernel<<<grid, 256, 0, stream>>>(zn1, zn2, ac, am, af, aca, ama, afa, rs, ms, asum);
    finalize_kernel<<<1, 256, 0, stream>>>(rs, ms, asum, d12, (float*)d_out);
}